// Round 2
// baseline (906.946 us; speedup 1.0000x reference)
//
#include <hip/hip_runtime.h>
#include <hip/hip_bf16.h>

typedef __bf16 bf16x8 __attribute__((ext_vector_type(8)));
typedef float floatx4 __attribute__((ext_vector_type(4)));

#define HH 128
#define WW 128
#define NCH 256
#define IMG 16384  // HH*WW

// LDS byte-offset helpers. src union tile: 384 px (16 rows x 24 cols) x 32ch
// bf16 = 64 B/px; tgt tile: 128 px (8 rows x 16 cols) x 32ch at offset 24576.
// 16-B chunks XOR-swizzled by (px>>1)&3 so b128 reads/writes at 64-B pixel
// stride stay at the wave64 2-lanes/bank floor.
__device__ __forceinline__ int src_off(int pu, int j) {
  return (pu << 6) + ((j ^ ((pu >> 1) & 3)) << 4);
}
__device__ __forceinline__ int tgt_off(int pt, int j) {
  return 24576 + (pt << 6) + ((j ^ ((pt >> 1) & 3)) << 4);
}

// fp32 -> bf16 round-to-nearest-even (inputs are finite; no NaN special-case)
__device__ __forceinline__ unsigned int bf16_rne(float x) {
  unsigned int u = __builtin_bit_cast(unsigned int, x);
  return (u + 0x7FFFu + ((u >> 16) & 1u)) >> 16;
}
__device__ __forceinline__ unsigned int pack2(float lo, float hi) {
  return bf16_rne(lo) | (bf16_rne(hi) << 16);
}

__global__ __launch_bounds__(256) void lfc_kernel(
    const float* __restrict__ fsrc,
    const float* __restrict__ ftgt,
    float* __restrict__ out)
{
  __shared__ char smem[49152];  // 32 KB staging, 48 KB extraction (aliased)

  const int tid  = threadIdx.x;
  const int lane = tid & 63;
  const int wv   = tid >> 6;
  const int b    = blockIdx.z;
  const int R0   = blockIdx.y << 3;   // 8-row region
  const int C0   = blockIdx.x << 4;   // 16-col region
  const int br   = (wv >> 1) << 2;    // wave block origin in region: 0 or 4
  const int bc   = (wv & 1) << 3;     // 0 or 8

  const size_t bbase = (size_t)b * NCH * IMG;

  // ---- tgt staging setup: px pt = (wv&1)*64+lane, ch-half = wv>>1 ----
  const int pt    = ((wv & 1) << 6) | lane;       // 0..127 region px
  const int thalf = wv >> 1;
  const float* tg = ftgt + bbase + (size_t)(thalf << 4) * IMG
      + (size_t)(R0 + (pt >> 4)) * WW + (size_t)(C0 + (pt & 15));
  const int tw0 = tgt_off(pt, (thalf << 1));
  const int tw1 = tgt_off(pt, (thalf << 1) + 1);

  // ---- src staging setup: pu0 = tid (all), pu1 = 256+tid (tid<128) ----
  const int pu0 = tid;
  const int gr0 = R0 - 4 + pu0 / 24;
  const int gc0 = C0 - 4 + pu0 % 24;
  const bool ok0 = (gr0 >= 0) && (gr0 < HH) && (gc0 >= 0) && (gc0 < WW);
  const float* sg0 = fsrc + bbase + (ptrdiff_t)(gr0 * WW + gc0);

  const int pu1 = 256 + tid;
  const bool have1 = tid < 128;
  const int gr1 = R0 - 4 + pu1 / 24;
  const int gc1 = C0 - 4 + pu1 % 24;
  const bool ok1 = have1 && (gr1 >= 0) && (gr1 < HH) && (gc1 >= 0) && (gc1 < WW);
  const float* sg1 = fsrc + bbase + (ptrdiff_t)(gr1 * WW + gc1);

  const int sw0_0 = src_off(pu0, 0), sw0_1 = src_off(pu0, 1);
  const int sw0_2 = src_off(pu0, 2), sw0_3 = src_off(pu0, 3);
  const int sw1_0 = src_off(pu1, 0), sw1_1 = src_off(pu1, 1);
  const int sw1_2 = src_off(pu1, 2), sw1_3 = src_off(pu1, 3);

  // ---- MFMA LDS read offsets (constant across K-steps) ----
  const int n  = lane & 15;   // A: m within M-tile / B: n within N-tile
  const int qq = lane >> 4;   // k-chunk
  int boff[12];
  #pragma unroll
  for (int t = 0; t < 12; ++t)
    boff[t] = src_off((br + t) * 24 + bc + n, qq);
  const int aoff0 = tgt_off((br + 0 + (n >> 3)) * 16 + bc + (n & 7), qq);
  const int aoff1 = tgt_off((br + 2 + (n >> 3)) * 16 + bc + (n & 7), qq);

  floatx4 acc0[12], acc1[12];
  const floatx4 zero4 = {0.f, 0.f, 0.f, 0.f};
  #pragma unroll
  for (int t = 0; t < 12; ++t) { acc0[t] = zero4; acc1[t] = zero4; }

  const size_t cstep = (size_t)32 * IMG;

  for (int ks = 0; ks < 8; ++ks) {
    // global fp32 loads, converted+packed to bf16 ch-pairs
    unsigned int tbuf[8] __attribute__((aligned(16)));
    #pragma unroll
    for (int i = 0; i < 8; ++i)
      tbuf[i] = pack2(tg[(size_t)(2 * i) * IMG], tg[(size_t)(2 * i + 1) * IMG]);

    unsigned int sbuf0[16] __attribute__((aligned(16)));
    #pragma unroll
    for (int i = 0; i < 16; ++i)
      sbuf0[i] = ok0 ? pack2(sg0[(size_t)(2 * i) * IMG],
                             sg0[(size_t)(2 * i + 1) * IMG]) : 0u;

    unsigned int sbuf1[16] __attribute__((aligned(16)));
    #pragma unroll
    for (int i = 0; i < 16; ++i)
      sbuf1[i] = ok1 ? pack2(sg1[(size_t)(2 * i) * IMG],
                             sg1[(size_t)(2 * i + 1) * IMG]) : 0u;

    __syncthreads();  // all waves done reading LDS of previous step
    *(uint4*)(smem + tw0) = ((const uint4*)tbuf)[0];
    *(uint4*)(smem + tw1) = ((const uint4*)tbuf)[1];
    *(uint4*)(smem + sw0_0) = ((const uint4*)sbuf0)[0];
    *(uint4*)(smem + sw0_1) = ((const uint4*)sbuf0)[1];
    *(uint4*)(smem + sw0_2) = ((const uint4*)sbuf0)[2];
    *(uint4*)(smem + sw0_3) = ((const uint4*)sbuf0)[3];
    if (have1) {
      *(uint4*)(smem + sw1_0) = ((const uint4*)sbuf1)[0];
      *(uint4*)(smem + sw1_1) = ((const uint4*)sbuf1)[1];
      *(uint4*)(smem + sw1_2) = ((const uint4*)sbuf1)[2];
      *(uint4*)(smem + sw1_3) = ((const uint4*)sbuf1)[3];
    }
    __syncthreads();  // tiles ready

    bf16x8 a0 = *(const bf16x8*)(smem + aoff0);
    bf16x8 a1 = *(const bf16x8*)(smem + aoff1);
    #pragma unroll
    for (int t = 0; t < 12; ++t) {
      bf16x8 bv = *(const bf16x8*)(smem + boff[t]);
      acc0[t] = __builtin_amdgcn_mfma_f32_16x16x32_bf16(a0, bv, acc0[t], 0, 0, 0);
      acc1[t] = __builtin_amdgcn_mfma_f32_16x16x32_bf16(a1, bv, acc1[t], 0, 0, 0);
    }
    tg += cstep; sg0 += cstep; sg1 += cstep;
  }

  // ---------------- extraction / relu / L2-normalize / store ----------------
  __syncthreads();  // before aliasing staging LDS with extraction buffers
  float* ew = (float*)smem + wv * 3072;  // 12 KB per wave: [t(12)][uc(16)][m(16)]
  const int mm = lane >> 2;   // pixel handled by this lane in read phase
  const int q  = lane & 3;    // displacement subgroup

  #pragma unroll
  for (int mt = 0; mt < 2; ++mt) {
    // dump this M-tile's Gram: D col(uc) = lane&15, row(m) = (lane>>4)*4+i
    #pragma unroll
    for (int t = 0; t < 12; ++t) {
      floatx4 v = (mt == 0) ? acc0[t] : acc1[t];
      *(floatx4*)((char*)ew + (t << 10) + ((lane & 15) << 6) + ((lane >> 4) << 4)) = v;
    }
    __syncthreads();
    const int px = (mt << 4) | mm;   // wave-block px 0..31
    const int r  = px >> 3;          // block row 0..3
    const int c  = px & 7;           // block col 0..7
    float vals[21];
    float ss = 0.f;
    #pragma unroll
    for (int j = 0; j < 21; ++j) {
      const int d = q + (j << 2);
      float v = 0.f;
      if (d < 81) {
        const int dh = d / 9, dw = d % 9;
        v = ew[(r + dh) * 256 + (c + dw) * 16 + mm];
        v = fmaxf(v, 0.f);
      }
      vals[j] = v;
      ss += v * v;
    }
    ss += __shfl_xor(ss, 1);
    ss += __shfl_xor(ss, 2);
    const float inv = 1.0f / fmaxf(sqrtf(ss), 1e-12f);
    const int gh = R0 + br + r;
    const int gw = C0 + bc + c;
    float* op = out + (size_t)b * 81 * IMG + (size_t)gh * WW + gw;
    #pragma unroll
    for (int j = 0; j < 21; ++j) {
      const int d = q + (j << 2);
      if (d < 81) op[(size_t)d * IMG] = vals[j] * inv;
    }
    __syncthreads();  // protect ew before next M-tile overwrites it
  }
}

extern "C" void kernel_launch(void* const* d_in, const int* in_sizes, int n_in,
                              void* d_out, int out_size, void* d_ws, size_t ws_size,
                              hipStream_t stream) {
  const float* fsrc = (const float*)d_in[0];  // feature_source
  const float* ftgt = (const float*)d_in[1];  // feature_target
  float* out = (float*)d_out;
  const int B = in_sizes[0] / (NCH * IMG);
  dim3 grid(WW / 16, HH / 8, B);
  lfc_kernel<<<grid, 256, 0, stream>>>(fsrc, ftgt, out);
}